// Round 3
// baseline (49.543 us; speedup 1.0000x reference)
//
#include <hip/hip_runtime.h>

#define N1 4096
#define N2 8192
#define FDIM 256
#define HDIM 128
#define OUTD 128

typedef float fx4 __attribute__((ext_vector_type(4)));

// mish(x) = x * tanh(softplus(x)) = x * ((1+e^x)^2 - 1) / ((1+e^x)^2 + 1)
__device__ __forceinline__ float mishf(float x) {
    float xc = fminf(x, 30.0f);          // tanh(softplus(x)) == 1.0f beyond this
    float e = __expf(xc);
    float w = 1.0f + e;
    float w2 = w * w;
    return x * ((w2 - 1.0f) / (w2 + 1.0f));
}

// One block, 512 threads: v_m[c] = dot(w_m[c,:], a[0:128]);  v_d[c] = dot(w_d[c,:], a[256:384])
__global__ void compute_v_kernel(const float* __restrict__ w_m,
                                 const float* __restrict__ w_d,
                                 const float* __restrict__ a,
                                 float* __restrict__ v /* 512 floats: v_m | v_d */) {
    int t = threadIdx.x;
    const float* wr;
    const float* av;
    if (t < 256) {
        wr = w_m + t * OUTD;
        av = a;                 // a1[:128]
    } else {
        wr = w_d + (t - 256) * OUTD;
        av = a + 2 * OUTD;      // a2[:128] = a[256:384]
    }
    float s = 0.f;
    #pragma unroll 8
    for (int o = 0; o < OUTD; ++o) s += wr[o] * av[o];
    v[t] = s;
}

// One wave (64 lanes) per row. Lane l handles cols [4l, 4l+4) via float4.
// x[i] = sum_c (am0*m+am1*m1+am2*m2)[i,c]*v_m[c] + sum_h m_h[i,h]*a[128+h]
__global__ void compute_xy_kernel(const float* __restrict__ m,  const float* __restrict__ m1,
                                  const float* __restrict__ m2, const float* __restrict__ m_h,
                                  const float* __restrict__ d,  const float* __restrict__ d1,
                                  const float* __restrict__ d2, const float* __restrict__ d_h,
                                  const float* __restrict__ a_m, const float* __restrict__ a_d,
                                  const float* __restrict__ a,
                                  const float* __restrict__ v,
                                  float* __restrict__ xy /* x[0..N1) then y[N1..N1+N2) */) {
    int gtid = blockIdx.x * blockDim.x + threadIdx.x;
    int row  = gtid >> 6;                 // one wave per row
    int lane = threadIdx.x & 63;

    const float *pm, *pm1, *pm2, *ph, *pa, *pv;
    float c0, c1, c2;
    int r;
    if (row < N1) {
        r = row;
        pm = m; pm1 = m1; pm2 = m2; ph = m_h;
        pa = a + OUTD;                    // a1[128:256]
        pv = v;
        c0 = a_m[0]; c1 = a_m[1]; c2 = a_m[2];
    } else {
        r = row - N1;
        pm = d; pm1 = d1; pm2 = d2; ph = d_h;
        pa = a + 2 * OUTD + HDIM;         // a2[128:256]
        pv = v + 256;
        c0 = a_d[0]; c1 = a_d[1]; c2 = a_d[2];
    }

    const fx4* q0 = (const fx4*)(pm  + (size_t)r * FDIM);
    const fx4* q1 = (const fx4*)(pm1 + (size_t)r * FDIM);
    const fx4* q2 = (const fx4*)(pm2 + (size_t)r * FDIM);
    const fx4* qv = (const fx4*)pv;

    fx4 v0 = q0[lane];
    fx4 v1 = q1[lane];
    fx4 v2 = q2[lane];
    fx4 vv = qv[lane];

    float val = (c0 * v0.x + c1 * v1.x + c2 * v2.x) * vv.x
              + (c0 * v0.y + c1 * v1.y + c2 * v2.y) * vv.y
              + (c0 * v0.z + c1 * v1.z + c2 * v2.z) * vv.z
              + (c0 * v0.w + c1 * v1.w + c2 * v2.w) * vv.w;

    if (lane < 32) {                      // 128 H-cols = 32 lanes x float4
        fx4 hv = ((const fx4*)(ph + (size_t)r * HDIM))[lane];
        fx4 av = ((const fx4*)pa)[lane];
        val += hv.x * av.x + hv.y * av.y + hv.z * av.z + hv.w * av.w;
    }

    #pragma unroll
    for (int off = 32; off > 0; off >>= 1) val += __shfl_down(val, off, 64);
    if (lane == 0) xy[row] = val;
}

// s[i,j] = mish(x[i] + y[j]), float4-vectorized along j, nontemporal stores.
__global__ void mish_bcast_kernel(const float* __restrict__ x,
                                  const float* __restrict__ y,
                                  fx4* __restrict__ out) {
    const unsigned JV = N2 / 4;                  // 2048 float4 per row
    const unsigned total = (unsigned)N1 * JV;    // 8,388,608
    const fx4* y4 = (const fx4*)y;
    for (unsigned vi = blockIdx.x * blockDim.x + threadIdx.x; vi < total;
         vi += gridDim.x * blockDim.x) {
        unsigned i  = vi >> 11;                  // / 2048 (wave-uniform: 2048 % 64 == 0)
        unsigned j4 = vi & 2047;
        float xi = x[i];
        fx4 yv = y4[j4];
        fx4 r;
        r.x = mishf(xi + yv.x);
        r.y = mishf(xi + yv.y);
        r.z = mishf(xi + yv.z);
        r.w = mishf(xi + yv.w);
        __builtin_nontemporal_store(r, &out[vi]);
    }
}

extern "C" void kernel_launch(void* const* d_in, const int* in_sizes, int n_in,
                              void* d_out, int out_size, void* d_ws, size_t ws_size,
                              hipStream_t stream) {
    const float* m   = (const float*)d_in[0];
    const float* m1  = (const float*)d_in[1];
    const float* m2  = (const float*)d_in[2];
    const float* m_h = (const float*)d_in[3];
    const float* d   = (const float*)d_in[4];
    const float* d1  = (const float*)d_in[5];
    const float* d2  = (const float*)d_in[6];
    const float* d_h = (const float*)d_in[7];
    const float* w_m = (const float*)d_in[8];
    const float* w_d = (const float*)d_in[9];
    const float* a_m = (const float*)d_in[10];
    const float* a_d = (const float*)d_in[11];
    const float* a   = (const float*)d_in[12];

    float* wsf = (float*)d_ws;
    float* v  = wsf;          // 512 floats
    float* xy = wsf + 512;    // 4096 + 8192 floats

    compute_v_kernel<<<1, 512, 0, stream>>>(w_m, w_d, a, v);
    // one wave per row: (N1+N2) waves = 12288 -> 3072 blocks of 256 threads
    compute_xy_kernel<<<(N1 + N2) / 4, 256, 0, stream>>>(m, m1, m2, m_h, d, d1, d2, d_h,
                                                         a_m, a_d, a, v, xy);
    mish_bcast_kernel<<<4096, 256, 0, stream>>>(xy, xy + N1, (fx4*)d_out);
}